// Round 6
// baseline (11.765 us; speedup 1.0000x reference)
//
#include <hip/hip_runtime.h>
#include <hip/hip_bf16.h>

// Problem constants (B=4, D=128, N=512, fp32)
#define PB 4
#define PD 128
#define PN 512

typedef __attribute__((ext_vector_type(2))) float f32x2;

__device__ __forceinline__ float f4get(const float4& v, int k) {
  const float* p = (const float*)&v;
  return p[k];
}

// One block = 2 full output rows (all N=512 cols) for one batch.
// grid = B*D/2 = 256 blocks (1/CU), 512 threads (8 waves -> 2/SIMD).
// t = tid&127 owns 4 contiguous cols (float4 loads); r = (tid>>7)&1 owns one
// of the block's 2 rows; dh = tid>>8 owns a 64-d half.
// Inner loop uses f32x2 accumulators + __builtin_elementwise_fma so the
// compiler emits v_pk_fma_f32 (2 FMA/instr): 256 VALU FMA-ops/thread instead
// of 512. x duplication exactly 2x (row pair, L1-merged).
// Tail: 8KB LDS pair-combine, wave-shuffle row max, half-active epilogue.
__global__ __launch_bounds__(512) void gcn_one(
    const float* __restrict__ x, const float* __restrict__ W1,
    const float* __restrict__ W2, const float* __restrict__ bias,
    float* __restrict__ out) {
  const int bid = blockIdx.x;
  const int b = bid >> 6;               // batch 0..3
  const int r0 = (bid & 63) << 1;       // first of the block's 2 rows
  const int tid = threadIdx.x;
  const int t = tid & 127;              // col-owner: cols [4t, 4t+4)
  const int r = (tid >> 7) & 1;         // row within pair
  const int dh = tid >> 8;              // d-half 0..1

  __shared__ float4 ws[2][2][32];       // [mat][row][d-chunk] : 2 KB
  __shared__ float4 red[2][128][2];     // [row][t][a|c]       : 8 KB
  __shared__ float rmax[2][2];          // [row][wave-half]

  // Stage 4 W-rows (W1,W2 x rows r0,r0+1), one float4 per thread (tid<128).
  if (tid < 128) {
    const int mat = tid >> 6;
    const int rr = (tid >> 5) & 1;
    const int c = tid & 31;
    const float* Wm = mat ? W2 : W1;
    ws[mat][rr][c] = *(const float4*)(Wm + (size_t)(r0 + rr) * PD + (c << 2));
  }
  __syncthreads();

  // x base: batch b, d-range [64*dh, 64*dh+64), cols [4t, 4t+4).
  const float* xp = x + (size_t)b * PD * PN + (size_t)(dh << 6) * PN + (t << 2);

  f32x2 aL = {0.f, 0.f}, aH = {0.f, 0.f};   // W1 dots, cols (0,1) / (2,3)
  f32x2 cL = {0.f, 0.f}, cH = {0.f, 0.f};   // W2 dots

#pragma unroll 4
  for (int dc = 0; dc < 16; ++dc) {     // 16 chunks x 4 d = 64 d per thread
    const int chunk = (dh << 4) + dc;
    const float4 w1v = ws[0][r][chunk]; // broadcast b128 reads, conflict-free
    const float4 w2v = ws[1][r][chunk];
    float4 xv[4];
#pragma unroll
    for (int k = 0; k < 4; ++k)
      xv[k] = *(const float4*)(xp + (size_t)((dc << 2) + k) * PN);
#pragma unroll
    for (int k = 0; k < 4; ++k) {
      const f32x2 xlo = {xv[k].x, xv[k].y};
      const f32x2 xhi = {xv[k].z, xv[k].w};
      const float s1 = f4get(w1v, k), s2 = f4get(w2v, k);
      const f32x2 u1 = {s1, s1};
      const f32x2 u2 = {s2, s2};
      aL = __builtin_elementwise_fma(u1, xlo, aL);   // v_pk_fma_f32
      aH = __builtin_elementwise_fma(u1, xhi, aH);
      cL = __builtin_elementwise_fma(u2, xlo, cL);
      cH = __builtin_elementwise_fma(u2, xhi, cH);
    }
  }

  // d-half 1 publishes partials; d-half 0 combines.
  if (dh == 1) {
    const float4 av = {aL.x, aL.y, aH.x, aH.y};
    const float4 cv = {cL.x, cL.y, cH.x, cH.y};
    red[r][t][0] = av;
    red[r][t][1] = cv;
  }
  __syncthreads();

  if (dh == 0) {
    const float4 ra = red[r][t][0], rc = red[r][t][1];
    aL.x += ra.x; aL.y += ra.y; aH.x += ra.z; aH.y += ra.w;
    cL.x += rc.x; cL.y += rc.y; cH.x += rc.z; cH.y += rc.w;

    // Row max of A: 4 local cols -> 64-lane wave -> 2 waves per row via LDS.
    float m = fmaxf(fmaxf(aL.x, aL.y), fmaxf(aH.x, aH.y));
#pragma unroll
    for (int off = 32; off > 0; off >>= 1)
      m = fmaxf(m, __shfl_xor(m, off));
    if ((t & 63) == 0) rmax[r][t >> 6] = m;
  }
  __syncthreads();

  if (dh == 0) {
    const float M = fmaxf(rmax[r][0], rmax[r][1]);
    const float bv = bias[r0 + r];
    float4 o;
    o.x = fmaxf(M + cL.x + bv - aL.x, 0.f);
    o.y = fmaxf(M + cL.y + bv - aL.y, 0.f);
    o.z = fmaxf(M + cH.x + bv - aH.x, 0.f);
    o.w = fmaxf(M + cH.y + bv - aH.y, 0.f);
    *(float4*)(out + (size_t)(b * PD + r0 + r) * PN + (t << 2)) = o;
  }
}

extern "C" void kernel_launch(void* const* d_in, const int* in_sizes, int n_in,
                              void* d_out, int out_size, void* d_ws, size_t ws_size,
                              hipStream_t stream) {
  const float* x = (const float*)d_in[0];
  const float* W1 = (const float*)d_in[1];
  const float* W2 = (const float*)d_in[2];
  const float* bias = (const float*)d_in[3];
  float* out = (float*)d_out;

  gcn_one<<<dim3(PB * PD / 2), dim3(512), 0, stream>>>(x, W1, W2, bias, out);
}

// Round 7
// 11.030 us; speedup vs baseline: 1.0666x; 1.0666x over previous
//
#include <hip/hip_runtime.h>
#include <hip/hip_bf16.h>

// Problem constants (B=4, D=128, N=512, fp32)
#define PB 4
#define PD 128
#define PN 512

__device__ __forceinline__ float f4get(const float4& v, int k) {
  const float* p = (const float*)&v;
  return p[k];
}

// One block = 2 full output rows (all N=512 cols) for one batch.
// grid = B*D/2 = 256 blocks (1/CU), 512 threads (8 waves -> 2/SIMD).
// Thread layout: t = tid&127 owns 4 contiguous cols (float4 loads);
// r = (tid>>7)&1 owns one of the block's 2 rows; dh = tid>>8 owns a
// 64-d half. Each thread: 1 row x 2 mats x 4 cols x 64 d = 256 FMA-instr.
// x duplication exactly 2x (row pair) -> L1-merged; L2 bytes/block = 256KB
// (the floor: ~1.9us at ~135 GB/s per-CU L2 share).
// Tail: 8KB LDS pair-combine, wave-shuffle row max, half-active epilogue.
// NOTE (R6): f32x2 v_pk_fma_f32 rewrite of this loop REGRESSED (10.9->11.8us)
// — pack/unpack churn around float4 loads; keep scalar fmaf.
__global__ __launch_bounds__(512) void gcn_one(
    const float* __restrict__ x, const float* __restrict__ W1,
    const float* __restrict__ W2, const float* __restrict__ bias,
    float* __restrict__ out) {
  const int bid = blockIdx.x;
  const int b = bid >> 6;               // batch 0..3
  const int r0 = (bid & 63) << 1;       // first of the block's 2 rows
  const int tid = threadIdx.x;
  const int t = tid & 127;              // col-owner: cols [4t, 4t+4)
  const int r = (tid >> 7) & 1;         // row within pair
  const int dh = tid >> 8;              // d-half 0..1

  __shared__ float4 ws[2][2][32];       // [mat][row][d-chunk] : 2 KB
  __shared__ float4 red[2][128][2];     // [row][t][a|c]       : 8 KB
  __shared__ float rmax[2][2];          // [row][wave-half]

  // Stage 4 W-rows (W1,W2 x rows r0,r0+1), one float4 per thread (tid<128).
  if (tid < 128) {
    const int mat = tid >> 6;
    const int rr = (tid >> 5) & 1;
    const int c = tid & 31;
    const float* Wm = mat ? W2 : W1;
    ws[mat][rr][c] = *(const float4*)(Wm + (size_t)(r0 + rr) * PD + (c << 2));
  }
  __syncthreads();

  // x base: batch b, d-range [64*dh, 64*dh+64), cols [4t, 4t+4).
  const float* xp = x + (size_t)b * PD * PN + (size_t)(dh << 6) * PN + (t << 2);

  float4 a = {0.f, 0.f, 0.f, 0.f};      // W1 row dot-products (4 cols)
  float4 c = {0.f, 0.f, 0.f, 0.f};      // W2 row dot-products

#pragma unroll 4
  for (int dc = 0; dc < 16; ++dc) {     // 16 chunks x 4 d = 64 d per thread
    const int chunk = (dh << 4) + dc;
    const float4 w1v = ws[0][r][chunk]; // broadcast b128 reads, conflict-free
    const float4 w2v = ws[1][r][chunk];
    float4 xv[4];
#pragma unroll
    for (int k = 0; k < 4; ++k)
      xv[k] = *(const float4*)(xp + (size_t)((dc << 2) + k) * PN);
#pragma unroll
    for (int k = 0; k < 4; ++k) {
      const float u1 = f4get(w1v, k), u2 = f4get(w2v, k);
      a.x = fmaf(u1, xv[k].x, a.x); a.y = fmaf(u1, xv[k].y, a.y);
      a.z = fmaf(u1, xv[k].z, a.z); a.w = fmaf(u1, xv[k].w, a.w);
      c.x = fmaf(u2, xv[k].x, c.x); c.y = fmaf(u2, xv[k].y, c.y);
      c.z = fmaf(u2, xv[k].z, c.z); c.w = fmaf(u2, xv[k].w, c.w);
    }
  }

  // d-half 1 publishes partials; d-half 0 combines.
  if (dh == 1) {
    red[r][t][0] = a;
    red[r][t][1] = c;
  }
  __syncthreads();

  if (dh == 0) {
    const float4 ra = red[r][t][0], rc = red[r][t][1];
    a.x += ra.x; a.y += ra.y; a.z += ra.z; a.w += ra.w;
    c.x += rc.x; c.y += rc.y; c.z += rc.z; c.w += rc.w;

    // Row max of A: 4 local cols -> 64-lane wave -> 2 waves per row via LDS.
    float m = fmaxf(fmaxf(a.x, a.y), fmaxf(a.z, a.w));
#pragma unroll
    for (int off = 32; off > 0; off >>= 1)
      m = fmaxf(m, __shfl_xor(m, off));
    if ((t & 63) == 0) rmax[r][t >> 6] = m;
  }
  __syncthreads();

  if (dh == 0) {
    const float M = fmaxf(rmax[r][0], rmax[r][1]);
    const float bv = bias[r0 + r];
    float4 o;
    o.x = fmaxf(M + c.x + bv - a.x, 0.f);
    o.y = fmaxf(M + c.y + bv - a.y, 0.f);
    o.z = fmaxf(M + c.z + bv - a.z, 0.f);
    o.w = fmaxf(M + c.w + bv - a.w, 0.f);
    *(float4*)(out + (size_t)(b * PD + r0 + r) * PN + (t << 2)) = o;
  }
}

extern "C" void kernel_launch(void* const* d_in, const int* in_sizes, int n_in,
                              void* d_out, int out_size, void* d_ws, size_t ws_size,
                              hipStream_t stream) {
  const float* x = (const float*)d_in[0];
  const float* W1 = (const float*)d_in[1];
  const float* W2 = (const float*)d_in[2];
  const float* bias = (const float*)d_in[3];
  float* out = (float*)d_out;

  gcn_one<<<dim3(PB * PD / 2), dim3(512), 0, stream>>>(x, W1, W2, bias, out);
}